// Round 5
// baseline (90.519 us; speedup 1.0000x reference)
//
#include <hip/hip_runtime.h>
#include <math.h>

// Balloon-Windkessel BOLD, 1000-step Euler. R5:
//  R4 post-mortem: VGPR_Count=28 proved the compiler sank the prefetch
//  ds_reads back to their uses (LDS read-only after barrier -> legal), so the
//  serial loop stayed LDS-latency-bound (~95 cy/step).
//  R5 removes ALL loads from the serial loop:
//   - (s,f) computed exactly in-lane (3 FMA linear recurrence == reference).
//   - q evicted: q_{t+1} = A_t q_t + B_t is a linear scan; phase 2 computes
//     A_t = 1 - c1*v_t^2.125, B_t = c1*f_t*E(f_t)/rho in parallel and runs a
//     chunked Hillis-Steele composite scan (250 chunks of 4 steps).
//  Serial core: 12 VALU + 1 ds_write_b64 per step, no loads, no transcendentals.

namespace {
constexpr int   kSteps  = 1000;
constexpr int   kChunks = kSteps / 4;        // 250 chunks of 4 steps
constexpr float kDt     = 0.01f;
constexpr float kOneMDt = 0.99f;             // 1 - dt
constexpr float kInvRho = 1.0f / 0.34f;
constexpr float kV0 = 0.02f, kK1 = 2.38f, kK2 = 2.0f, kK3 = 0.48f;
constexpr float kL2OneMR = -0.5994620704f;   // log2(0.66)
// quadratic Taylor of (1+x)^3.125 (validated R4: absmax 1.2e-7)
constexpr float kA1 = 3.125f, kA2 = 3.3203125f;
constexpr float kPw = 2.125f;                // A_t = 1 - c1 * v_t^2.125
}

__global__ __launch_bounds__(256)
void bold_kernel(const void* __restrict__ mtt_raw, float* __restrict__ out) {
    __shared__ float2 VF[kSteps + 1];        // (v_t, f_t), t = 0..1000
    __shared__ float2 SC[256];               // chunk composites (P,Q)
    const int tid = threadIdx.x;

    unsigned bits = *(const unsigned*)mtt_raw;
    float mtt = ((bits & 0xFFFFu) == 0u) ? __uint_as_float(bits)
                                         : __uint_as_float(bits << 16);
    const float c1 = kDt / mtt;

    // ---- Phase 1: serial (s,f,v); p ~ v^3.125 (Taylor), r ~ 1/v (Newton) ----
    if (tid == 0) {
        float s = 0.f, f = 1.f, v = 1.f, p = 1.f, r = 1.f;
        VF[0] = make_float2(1.f, 1.f);
        #pragma unroll 4
        for (int t = 0; t < kSteps; ++t) {
            float t2  = f - p;                       // f_t - v_t^3.125
            float d   = c1 * t2;                     // dv
            float del = d * r;                       // dv / v_t
            float g   = fmaf(kA2, del, kA1);
            float pd  = p * del;
            float vn  = v + d;
            float pn  = fmaf(pd, g, p);              // p*(1+del)^3.125
            float t0  = fmaf(-vn, r, 2.0f);
            float fn  = fmaf(kDt, s, f);             // exact reference f-update
            float sn  = fmaf(kOneMDt, s, fmaf(-kDt, f, 0.02f));
            float rn  = r * t0;                      // Newton 1/v_{t+1}
            VF[t + 1] = make_float2(vn, fn);
            s = sn; f = fn; v = vn; p = pn; r = rn;
        }
    }
    __syncthreads();

    // ---- Phase 2a: per-step (A_t, B_t) + chunk composite (4 steps/thread) ----
    float A[4], B[4], Vn[4];
    float Pc = 1.0f, Qc = 0.0f;                      // identity composite
    if (tid < kChunks) {
        #pragma unroll
        for (int k = 0; k < 4; ++k) {
            int t = 4 * tid + k;
            float2 vf  = VF[t];
            float2 vf1 = VF[t + 1];
            float vt = vf.x, ft = vf.y;
            float At = fmaf(-c1,
                __builtin_amdgcn_exp2f(kPw * __builtin_amdgcn_logf(vt)), 1.0f);
            float E1 = __builtin_amdgcn_exp2f(kL2OneMR * __builtin_amdgcn_rcpf(ft));
            float Bt = (c1 * kInvRho) * ft * (1.0f - E1);
            A[k] = At; B[k] = Bt; Vn[k] = vf1.x;
            Qc = fmaf(At, Qc, Bt);                   // (At,Bt) ∘ (Pc,Qc)
            Pc = At * Pc;
        }
    }
    float2 x = make_float2(Pc, Qc);
    SC[tid] = x;
    __syncthreads();

    // ---- Phase 2b: Hillis-Steele inclusive scan of composites (256 wide) ----
    #pragma unroll
    for (int off = 1; off < 256; off <<= 1) {
        float2 y = make_float2(1.f, 0.f);
        if (tid >= off) y = SC[tid - off];
        __syncthreads();
        x = make_float2(x.x * y.x, fmaf(x.x, y.y, x.y));   // x ∘ y (y earlier)
        SC[tid] = x;
        __syncthreads();
    }

    // ---- Phase 2c: replay chunk + BOLD readout, float4 coalesced store ----
    if (tid < kChunks) {
        float q = 1.0f;                              // q_0
        if (tid > 0) {
            float2 e = SC[tid - 1];                  // composite of chunks < tid
            q = e.x + e.y;                           // q_{4*tid} (q_0 = 1)
        }
        float4 y4;
        float yv[4];
        #pragma unroll
        for (int k = 0; k < 4; ++k) {
            q = fmaf(A[k], q, B[k]);                 // q_{t+1}
            float vn = Vn[k];
            yv[k] = kV0 * (kK1 * (1.0f - q)
                         + kK2 * fmaf(-q, __builtin_amdgcn_rcpf(vn), 1.0f)
                         + kK3 * (1.0f - vn));
        }
        y4.x = yv[0]; y4.y = yv[1]; y4.z = yv[2]; y4.w = yv[3];
        ((float4*)out)[tid] = y4;
    }
}

extern "C" void kernel_launch(void* const* d_in, const int* in_sizes, int n_in,
                              void* d_out, int out_size, void* d_ws, size_t ws_size,
                              hipStream_t stream) {
    bold_kernel<<<dim3(1), dim3(256), 0, stream>>>(d_in[0], (float*)d_out);
}

// Round 6
// 81.920 us; speedup vs baseline: 1.1050x; 1.1050x over previous
//
#include <hip/hip_runtime.h>
#include <math.h>

// Balloon-Windkessel BOLD, 1000-step Euler. R6:
//  R3/R4/R5 all measured ~95-120 cy/step == LDS single-outstanding latency:
//  every variant had exactly one LDS op per serial step with hazard distance
//  of 1 iteration (R3 read-at-use; R4 compiler re-sank prefetch reads;
//  R5 ds_write WAR on recycled regs -- VGPR_Count=12 was the proof).
//  R6: serial loop stores ONLY v, in 8-step register bursts (2x ds_write_b128)
//  with TWO alternating register buffers so burst sources are rewritten a full
//  8 steps (~200 cy) after issue -> WAR hits retired writes. f_t is rebuilt in
//  phase 2 from the R4-validated closed form; q via the R5-validated composite
//  scan (now shuffle-based, 2 barriers). f_t/B_t precomputed pre-barrier,
//  overlapping the serial phase.

namespace {
constexpr int   kSteps  = 1000;
constexpr int   kChunks = kSteps / 4;        // 250 chunks of 4 steps
constexpr float kDt     = 0.01f;
constexpr float kInvRho = 1.0f / 0.34f;
constexpr float kV0 = 0.02f, kK1 = 2.38f, kK2 = 2.0f, kK3 = 0.48f;
// discrete-eigen closed form for f_t (R4-validated, absmax 1.2e-7):
constexpr float kLog2R    = -0.0071769251f;   // log2(|lambda|)
constexpr float kThetaRev =  0.0013852133f;   // arg(lambda)/(2pi), v_sin units
constexpr float kCB       = -0.57735026919f;  // -1/sqrt(3)
constexpr float kL2OneMR  = -0.5994620704f;   // log2(0.66)
// quadratic Taylor of (1+x)^3.125 (R4/R5-validated)
constexpr float kA1 = 3.125f, kA2 = 3.3203125f;
constexpr float kPw = 2.125f;                 // A_t = 1 - c1 * v_t^2.125
}

__global__ __launch_bounds__(256)
void bold_kernel(const void* __restrict__ mtt_raw, float* __restrict__ out) {
    __shared__ __align__(16) float Vv[kSteps];   // Vv[t] = v_{t+1}
    __shared__ float2 SC[4];                     // per-wave scan aggregates
    const int tid  = threadIdx.x;
    const int lane = tid & 63, wid = tid >> 6;

    unsigned bits = *(const unsigned*)mtt_raw;
    float mtt = ((bits & 0xFFFFu) == 0u) ? __uint_as_float(bits)
                                         : __uint_as_float(bits << 16);
    const float c1 = kDt / mtt;

    // ---- Pre-barrier (all threads, overlaps serial phase): f_t, B_t ----
    float Bt[4], Ft[4];
    if (tid < kChunks) {
        #pragma unroll
        for (int k = 0; k < 4; ++k) {
            float tf = (float)(4 * tid + k);
            float rt = __builtin_amdgcn_exp2f(tf * kLog2R);
            float ar = tf * kThetaRev;
            float sn = __builtin_amdgcn_sinf(ar);
            float cs = __builtin_amdgcn_cosf(ar);
            float ft = fmaf(rt, fmaf(kCB, sn, -cs), 2.0f);      // exact f_t
            float E1 = __builtin_amdgcn_exp2f(kL2OneMR * __builtin_amdgcn_rcpf(ft));
            Ft[k] = ft;
            Bt[k] = (c1 * kInvRho) * ft * (1.0f - E1);          // c1*f*E/rho
        }
    }

    // ---- Phase 1 (tid 0): serial v; 12 VALU/step, burst LDS writes ----
    if (tid == 0) {
        float s = 0.f, f = 1.f, v = 1.f, p = 1.f, r = 1.f;
        #define STEP8(VR)                                            \
            _Pragma("unroll")                                        \
            for (int k = 0; k < 8; ++k) {                            \
                float t2  = f - p;                                   \
                float d   = c1 * t2;                                 \
                float del = d * r;                                   \
                float g   = fmaf(kA2, del, kA1);                     \
                float pd  = p * del;                                 \
                float vn  = v + d;                                   \
                float pn  = fmaf(pd, g, p);                          \
                float t0  = fmaf(-vn, r, 2.0f);                      \
                float rn  = r * t0;                                  \
                float fn  = fmaf(kDt, s, f);                         \
                float sn  = fmaf(0.99f, s, fmaf(-kDt, f, 0.02f));    \
                VR[k] = vn;                                          \
                s = sn; f = fn; v = vn; p = pn; r = rn;              \
            }
        #define BURST(VR, base)                                              \
            {                                                                \
                float4* dst = (float4*)&Vv[(base)];                          \
                dst[0] = make_float4(VR[0], VR[1], VR[2], VR[3]);            \
                dst[1] = make_float4(VR[4], VR[5], VR[6], VR[7]);            \
            }
        float vrA[8], vrB[8];
        // 62 double-blocks (16 steps) + 1 single block = 125*8 = 1000 steps
        for (int db = 0; db < 62; ++db) {
            STEP8(vrA); BURST(vrA, 16 * db);
            STEP8(vrB); BURST(vrB, 16 * db + 8);
        }
        STEP8(vrA); BURST(vrA, 992);
        #undef STEP8
        #undef BURST
    }
    __syncthreads();

    // ---- Phase 2a: A_t + chunk composite (4 steps/thread) ----
    float A[4], Vn[4];
    float Pc = 1.0f, Qc = 0.0f;                  // identity composite
    if (tid < kChunks) {
        #pragma unroll
        for (int k = 0; k < 4; ++k) {
            int t = 4 * tid + k;
            float vt = (t == 0) ? 1.0f : Vv[t - 1];
            float At = fmaf(-c1,
                __builtin_amdgcn_exp2f(kPw * __builtin_amdgcn_logf(vt)), 1.0f);
            A[k] = At; Vn[k] = Vv[t];
            Qc = fmaf(At, Qc, Bt[k]);            // (At,Bt) o (Pc,Qc)
            Pc = At * Pc;
        }
    }

    // ---- Phase 2b: shuffle-based inclusive scan of composites ----
    float xP = Pc, xQ = Qc;
    #pragma unroll
    for (int off = 1; off < 64; off <<= 1) {
        float yP = __shfl_up(xP, off, 64);
        float yQ = __shfl_up(xQ, off, 64);
        if (lane >= off) { xQ = fmaf(xP, yQ, xQ); xP *= yP; }
    }
    if (lane == 63) SC[wid] = make_float2(xP, xQ);
    __syncthreads();

    // exclusive-within-wave prefix
    float eP = __shfl_up(xP, 1, 64);
    float eQ = __shfl_up(xQ, 1, 64);
    if (lane == 0) { eP = 1.0f; eQ = 0.0f; }
    // prefix of preceding waves (wid <= 3 -> at most 3 composes)
    float wP = 1.0f, wQ = 0.0f;
    for (int w = 0; w < wid; ++w) {
        float2 a = SC[w];                        // later block a over earlier acc
        wQ = fmaf(a.x, wQ, a.y);
        wP = a.x * wP;
    }
    // total exclusive prefix: e (later) o w (earlier)
    float EP = eP * wP;
    float EQ = fmaf(eP, wQ, eQ);

    // ---- Phase 2c: replay chunk + BOLD readout, float4 store ----
    if (tid < kChunks) {
        float q = EP + EQ;                       // q_{4*tid} (q_0 = 1)
        float yv[4];
        #pragma unroll
        for (int k = 0; k < 4; ++k) {
            q = fmaf(A[k], q, Bt[k]);            // q_{t+1}
            float vn = Vn[k];
            yv[k] = kV0 * (kK1 * (1.0f - q)
                         + kK2 * fmaf(-q, __builtin_amdgcn_rcpf(vn), 1.0f)
                         + kK3 * (1.0f - vn));
        }
        ((float4*)out)[tid] = make_float4(yv[0], yv[1], yv[2], yv[3]);
    }
}

extern "C" void kernel_launch(void* const* d_in, const int* in_sizes, int n_in,
                              void* d_out, int out_size, void* d_ws, size_t ws_size,
                              hipStream_t stream) {
    bold_kernel<<<dim3(1), dim3(256), 0, stream>>>(d_in[0], (float*)d_out);
}

// Round 7
// 56.140 us; speedup vs baseline: 1.6124x; 1.4592x over previous
//
#include <hip/hip_runtime.h>
#include <math.h>

// Balloon-Windkessel BOLD, 1000-step Euler. R7: parallel-in-time Newton.
//  R3-R6 post-mortem: serial-phase cost ~= 7 cy per instruction regardless of
//  instruction type (118/95/107/86 cy/step at 15/13/13/12 instrs) -- a lone
//  wave issues dependent VALU at ~4-7 cy cadence with no co-resident waves to
//  hide it. So R7 ELIMINATES the serial phase:
//  Newton on the whole trajectory: linearize v_{t+1}=v_t+c1(f_t - v_t^3.125)
//  around guess {v'}: x_t = A_t x_{t-1} + B_t, A_t = 1-3.125*c1*v'^2.125,
//  B_t = F_t + 2.125*c1*v'^3.125 -- an associative-scan-solvable linear
//  recurrence (R5/R6-validated machinery). e -> ~e^2 per sweep, e0 ~ 0.25 ->
//  4 sweeps to fp32-exact; 6 fixed sweeps for margin (graph-safe).
//  f_t closed form (R4-validated); q via one more scan pass (R6-validated).

namespace {
constexpr int   kSteps  = 1000;
constexpr int   kChunks = 250;               // 4 steps per thread
constexpr int   kSweeps = 6;
constexpr float kDt     = 0.01f;
constexpr float kInvRho = 1.0f / 0.34f;
constexpr float kV0 = 0.02f, kK1 = 2.38f, kK2 = 2.0f, kK3 = 0.48f;
// discrete-eigen closed form for f_t (R4-validated):
constexpr float kLog2R    = -0.0071769251f;   // log2(|lambda|)
constexpr float kThetaRev =  0.0013852133f;   // arg(lambda)/(2pi), v_sin units
constexpr float kCB       = -0.57735026919f;  // -1/sqrt(3)
constexpr float kL2OneMR  = -0.5994620704f;   // log2(0.66)
constexpr float kPwm1     = 2.125f;           // 3.125 - 1
}

__global__ __launch_bounds__(256)
void bold_kernel(const void* __restrict__ mtt_raw, float* __restrict__ out) {
    __shared__ __align__(16) float Xb[kSteps];   // x_t = v_{t+1}, t=0..999
    __shared__ float2 SC[4];                     // per-wave scan aggregates
    const int tid  = threadIdx.x;
    const int lane = tid & 63, wid = tid >> 6;

    unsigned bits = *(const unsigned*)mtt_raw;
    float mtt = ((bits & 0xFFFFu) == 0u) ? __uint_as_float(bits)
                                         : __uint_as_float(bits << 16);
    const float c1   = kDt / mtt;
    const float c31  = 3.125f * c1;
    const float c21  = kPwm1 * c1;

    // ---- Precompute (registers): Fc[k] = c1*f_t, Bq[k] = c1*f*E/rho ----
    float Fc[4], Bq[4];
    if (tid < kChunks) {
        #pragma unroll
        for (int k = 0; k < 4; ++k) {
            float tf = (float)(4 * tid + k);
            float rt = __builtin_amdgcn_exp2f(tf * kLog2R);
            float ar = tf * kThetaRev;
            float sn = __builtin_amdgcn_sinf(ar);
            float cs = __builtin_amdgcn_cosf(ar);
            float ft = fmaf(rt, fmaf(kCB, sn, -cs), 2.0f);      // exact f_t
            float E1 = __builtin_amdgcn_exp2f(kL2OneMR * __builtin_amdgcn_rcpf(ft));
            Fc[k] = c1 * ft;
            Bq[k] = (c1 * kInvRho) * ft * (1.0f - E1);
        }
        ((float4*)Xb)[tid] = make_float4(1.f, 1.f, 1.f, 1.f);   // initial guess
    }
    __syncthreads();

    float A[4], B[4];

    // ---- Newton sweeps: linearize, scan-solve, update trajectory ----
    for (int sweep = 0; sweep < kSweeps; ++sweep) {
        float Pc = 1.0f, Qc = 0.0f;
        if (tid < kChunks) {
            float4 X   = ((float4*)Xb)[tid];
            float pred = (tid == 0) ? 1.0f : Xb[4 * tid - 1];
            float vb[4] = {pred, X.x, X.y, X.z};    // v'_t for t=4i..4i+3
            #pragma unroll
            for (int k = 0; k < 4; ++k) {
                float vt = vb[k];
                float w  = __builtin_amdgcn_exp2f(
                               kPwm1 * __builtin_amdgcn_logf(vt)); // v^2.125
                float p3 = w * vt;                                 // v^3.125
                float At = fmaf(-c31, w, 1.0f);
                float Bt = fmaf(c21, p3, Fc[k]);
                A[k] = At; B[k] = Bt;
                Qc = fmaf(At, Qc, Bt);              // (At,Bt) o (Pc,Qc)
                Pc = At * Pc;
            }
        }
        // wave-level inclusive scan of composites (R6-validated)
        float xP = Pc, xQ = Qc;
        #pragma unroll
        for (int off = 1; off < 64; off <<= 1) {
            float yP = __shfl_up(xP, off, 64);
            float yQ = __shfl_up(xQ, off, 64);
            if (lane >= off) { xQ = fmaf(xP, yQ, xQ); xP *= yP; }
        }
        if (lane == 63) SC[wid] = make_float2(xP, xQ);
        __syncthreads();
        float eP = __shfl_up(xP, 1, 64);
        float eQ = __shfl_up(xQ, 1, 64);
        if (lane == 0) { eP = 1.0f; eQ = 0.0f; }
        float wP = 1.0f, wQ = 0.0f;
        for (int w2 = 0; w2 < wid; ++w2) {          // <=3 composes
            float2 a = SC[w2];
            wQ = fmaf(a.x, wQ, a.y);
            wP = a.x * wP;
        }
        float EP = eP * wP;
        float EQ = fmaf(eP, wQ, eQ);
        // replay chunk: x_{4i-1} = EP*1 + EQ  (x_{-1} = v_0 = 1)
        if (tid < kChunks) {
            float x = EP + EQ;
            float4 Xn;
            x = fmaf(A[0], x, B[0]); Xn.x = x;
            x = fmaf(A[1], x, B[1]); Xn.y = x;
            x = fmaf(A[2], x, B[2]); Xn.z = x;
            x = fmaf(A[3], x, B[3]); Xn.w = x;
            ((float4*)Xb)[tid] = Xn;
        }
        __syncthreads();
    }

    // ---- q pass: A^q_t = 1 - c1*v_t^2.125, B^q precomputed; scan + y ----
    float Vx[4];
    {
        float Pc = 1.0f, Qc = 0.0f;
        if (tid < kChunks) {
            float4 X   = ((float4*)Xb)[tid];
            float pred = (tid == 0) ? 1.0f : Xb[4 * tid - 1];
            float vb[4] = {pred, X.x, X.y, X.z};
            Vx[0] = X.x; Vx[1] = X.y; Vx[2] = X.z; Vx[3] = X.w;
            #pragma unroll
            for (int k = 0; k < 4; ++k) {
                float w  = __builtin_amdgcn_exp2f(
                               kPwm1 * __builtin_amdgcn_logf(vb[k]));
                float At = fmaf(-c1, w, 1.0f);
                A[k] = At;
                Qc = fmaf(At, Qc, Bq[k]);
                Pc = At * Pc;
            }
        }
        float xP = Pc, xQ = Qc;
        #pragma unroll
        for (int off = 1; off < 64; off <<= 1) {
            float yP = __shfl_up(xP, off, 64);
            float yQ = __shfl_up(xQ, off, 64);
            if (lane >= off) { xQ = fmaf(xP, yQ, xQ); xP *= yP; }
        }
        if (lane == 63) SC[wid] = make_float2(xP, xQ);
        __syncthreads();
        float eP = __shfl_up(xP, 1, 64);
        float eQ = __shfl_up(xQ, 1, 64);
        if (lane == 0) { eP = 1.0f; eQ = 0.0f; }
        float wP = 1.0f, wQ = 0.0f;
        for (int w2 = 0; w2 < wid; ++w2) {
            float2 a = SC[w2];
            wQ = fmaf(a.x, wQ, a.y);
            wP = a.x * wP;
        }
        float EP = eP * wP;
        float EQ = fmaf(eP, wQ, eQ);
        if (tid < kChunks) {
            float q = EP + EQ;                      // q_{4i} (q_0 = 1)
            float yv[4];
            #pragma unroll
            for (int k = 0; k < 4; ++k) {
                q = fmaf(A[k], q, Bq[k]);           // q_{t+1}
                float vn = Vx[k];
                yv[k] = kV0 * (kK1 * (1.0f - q)
                             + kK2 * fmaf(-q, __builtin_amdgcn_rcpf(vn), 1.0f)
                             + kK3 * (1.0f - vn));
            }
            ((float4*)out)[tid] = make_float4(yv[0], yv[1], yv[2], yv[3]);
        }
    }
}

extern "C" void kernel_launch(void* const* d_in, const int* in_sizes, int n_in,
                              void* d_out, int out_size, void* d_ws, size_t ws_size,
                              hipStream_t stream) {
    bold_kernel<<<dim3(1), dim3(256), 0, stream>>>(d_in[0], (float*)d_out);
}

// Round 8
// 53.496 us; speedup vs baseline: 1.6921x; 1.0494x over previous
//
#include <hip/hip_runtime.h>
#include <math.h>

// Balloon-Windkessel BOLD, 1000-step Euler. R8:
//  R7 (parallel-in-time Newton, 7 scan passes) left ~10us; breakdown showed
//  each pass dominated by 12 serial ds_bpermute shuffles (~60-120cy each) +
//  dependent LDS combines, not VALU. R8:
//   - DPP Kogge-Stone wave scan (row_shr:1/2/4/8 + row_bcast:15/31) -> scan
//     stages at VALU latency instead of LDS latency.
//   - 5 passes: sweep0 linearized at v==1 (closed-form A,B, no trans);
//     sweeps 1-3 full Newton; sweep4 fused with the q-scan (A_q = 1-c1*w
//     reuses w=v^2.125 already computed; q linearized at e~5e-7 -> err ~1e-8).
//   - trajectory chunk lives in REGISTERS across sweeps (pred via shfl_up +
//     1-float LDS slot at wave boundaries) -- no float4 LDS round trip.

namespace {
constexpr int   kChunks = 250;               // 4 steps per thread
constexpr float kDt     = 0.01f;
constexpr float kInvRho = 1.0f / 0.34f;
constexpr float kV0 = 0.02f, kK1 = 2.38f, kK2 = 2.0f, kK3 = 0.48f;
// discrete-eigen closed form for f_t (R4-validated):
constexpr float kLog2R    = -0.0071769251f;   // log2(|lambda|)
constexpr float kThetaRev =  0.0013852133f;   // arg(lambda)/(2pi), v_sin units
constexpr float kCB       = -0.57735026919f;  // -1/sqrt(3)
constexpr float kL2OneMR  = -0.5994620704f;   // log2(0.66)
constexpr float kPwm1     = 2.125f;           // 3.125 - 1
}

template<int Ctrl, int RowMask>
__device__ __forceinline__ float dppf(float x, float ident) {
    return __int_as_float(__builtin_amdgcn_update_dpp(
        __float_as_int(ident), __float_as_int(x), Ctrl, RowMask, 0xF, false));
}

// inclusive wave64 scan of linear-map composites (P,Q): x <- x o y (y earlier)
__device__ __forceinline__ void wave_scan2(float& xP, float& xQ) {
    #define ST(C, M) { float yP = dppf<C, M>(xP, 1.0f);            \
                       float yQ = dppf<C, M>(xQ, 0.0f);            \
                       xQ = fmaf(xP, yQ, xQ); xP *= yP; }
    ST(0x111, 0xF) ST(0x112, 0xF) ST(0x114, 0xF) ST(0x118, 0xF)
    ST(0x142, 0xA) ST(0x143, 0xC)
    #undef ST
}
__device__ __forceinline__ void wave_scan4(float& xP, float& xQ,
                                           float& uP, float& uQ) {
    #define ST(C, M) { float yP = dppf<C, M>(xP, 1.0f);            \
                       float yQ = dppf<C, M>(xQ, 0.0f);            \
                       float zP = dppf<C, M>(uP, 1.0f);            \
                       float zQ = dppf<C, M>(uQ, 0.0f);            \
                       xQ = fmaf(xP, yQ, xQ); xP *= yP;            \
                       uQ = fmaf(uP, zQ, uQ); uP *= zP; }
    ST(0x111, 0xF) ST(0x112, 0xF) ST(0x114, 0xF) ST(0x118, 0xF)
    ST(0x142, 0xA) ST(0x143, 0xC)
    #undef ST
}

__global__ __launch_bounds__(256)
void bold_kernel(const void* __restrict__ mtt_raw, float* __restrict__ out) {
    __shared__ float2 SCv[4];     // per-wave v-composite aggregates
    __shared__ float2 SCq[4];     // per-wave q-composite aggregates (last pass)
    __shared__ float  SCX[4];     // per-wave last trajectory value
    const int tid  = threadIdx.x;
    const int lane = tid & 63, wid = tid >> 6;

    unsigned bits = *(const unsigned*)mtt_raw;
    float mtt = ((bits & 0xFFFFu) == 0u) ? __uint_as_float(bits)
                                         : __uint_as_float(bits << 16);
    const float c1  = kDt / mtt;
    const float c31 = 3.125f * c1;
    const float c21 = kPwm1 * c1;

    // ---- Prologue: Fc[k] = c1*f_t (closed-form f), Bq[k] = c1*f*E/rho ----
    float Fc[4] = {0, 0, 0, 0}, Bq[4] = {0, 0, 0, 0};
    if (tid < kChunks) {
        #pragma unroll
        for (int k = 0; k < 4; ++k) {
            float tf = (float)(4 * tid + k);
            float rt = __builtin_amdgcn_exp2f(tf * kLog2R);
            float ar = tf * kThetaRev;
            float sn = __builtin_amdgcn_sinf(ar);
            float cs = __builtin_amdgcn_cosf(ar);
            float ft = fmaf(rt, fmaf(kCB, sn, -cs), 2.0f);      // exact f_t
            float E1 = __builtin_amdgcn_exp2f(kL2OneMR * __builtin_amdgcn_rcpf(ft));
            Fc[k] = c1 * ft;
            Bq[k] = (c1 * kInvRho) * ft * (1.0f - E1);
        }
    }

    float4 X = make_float4(1.f, 1.f, 1.f, 1.f);   // trajectory chunk (regs)
    float A[4] = {1, 1, 1, 1}, B[4] = {0, 0, 0, 0};

    // ---- Sweep 0: linearize at v==1 -> closed-form A,B, no transcendentals --
    {
        float Pc = 1.0f, Qc = 0.0f;
        const float A0 = 1.0f - c31;
        if (tid < kChunks) {
            #pragma unroll
            for (int k = 0; k < 4; ++k) {
                A[k] = A0; B[k] = Fc[k] + c21;
                Qc = fmaf(A0, Qc, B[k]); Pc *= A0;
            }
        }
        float xP = Pc, xQ = Qc;
        wave_scan2(xP, xQ);
        if (lane == 63) SCv[wid] = make_float2(xP, xQ);
        __syncthreads();
        float eP = __shfl_up(xP, 1, 64), eQ = __shfl_up(xQ, 1, 64);
        if (lane == 0) { eP = 1.f; eQ = 0.f; }
        float2 a0 = SCv[0], a1 = SCv[1], a2 = SCv[2];  // independent loads
        float wP = 1.f, wQ = 0.f;
        if (wid >= 1) { wP = a0.x; wQ = a0.y; }
        if (wid >= 2) { wQ = fmaf(a1.x, wQ, a1.y); wP *= a1.x; }
        if (wid >= 3) { wQ = fmaf(a2.x, wQ, a2.y); wP *= a2.x; }
        float x = fmaf(eP, wQ, eQ) + eP * wP;          // x_{4tid-1} (x_-1 = 1)
        x = fmaf(A[0], x, B[0]); X.x = x;
        x = fmaf(A[1], x, B[1]); X.y = x;
        x = fmaf(A[2], x, B[2]); X.z = x;
        x = fmaf(A[3], x, B[3]); X.w = x;
        if (lane == 63) SCX[wid] = X.w;
        __syncthreads();
    }

    // ---- Sweeps 1..3: full Newton, DPP scan ----
    for (int sw = 0; sw < 3; ++sw) {
        float predw = __shfl_up(X.w, 1, 64);
        float oldw  = (wid == 0) ? 1.0f : SCX[wid - 1];
        if (lane == 0) predw = oldw;
        float Pc = 1.0f, Qc = 0.0f;
        if (tid < kChunks) {
            float vb[4] = {predw, X.x, X.y, X.z};
            #pragma unroll
            for (int k = 0; k < 4; ++k) {
                float w  = __builtin_amdgcn_exp2f(
                               kPwm1 * __builtin_amdgcn_logf(vb[k])); // v^2.125
                float p3 = w * vb[k];                                 // v^3.125
                float At = fmaf(-c31, w, 1.0f);
                float Bt = fmaf(c21, p3, Fc[k]);
                A[k] = At; B[k] = Bt;
                Qc = fmaf(At, Qc, Bt); Pc = At * Pc;
            }
        }
        float xP = Pc, xQ = Qc;
        wave_scan2(xP, xQ);
        if (lane == 63) SCv[wid] = make_float2(xP, xQ);
        __syncthreads();
        float eP = __shfl_up(xP, 1, 64), eQ = __shfl_up(xQ, 1, 64);
        if (lane == 0) { eP = 1.f; eQ = 0.f; }
        float2 a0 = SCv[0], a1 = SCv[1], a2 = SCv[2];
        float wP = 1.f, wQ = 0.f;
        if (wid >= 1) { wP = a0.x; wQ = a0.y; }
        if (wid >= 2) { wQ = fmaf(a1.x, wQ, a1.y); wP *= a1.x; }
        if (wid >= 3) { wQ = fmaf(a2.x, wQ, a2.y); wP *= a2.x; }
        float x = fmaf(eP, wQ, eQ) + eP * wP;
        x = fmaf(A[0], x, B[0]); X.x = x;
        x = fmaf(A[1], x, B[1]); X.y = x;
        x = fmaf(A[2], x, B[2]); X.z = x;
        x = fmaf(A[3], x, B[3]); X.w = x;
        if (lane == 63) SCX[wid] = X.w;
        __syncthreads();
    }

    // ---- Sweep 4 (final): Newton sweep FUSED with q-scan + readout ----
    {
        float predw = __shfl_up(X.w, 1, 64);
        float oldw  = (wid == 0) ? 1.0f : SCX[wid - 1];
        if (lane == 0) predw = oldw;
        float Pv = 1.f, Qv = 0.f, Pq = 1.f, Qq = 0.f;
        float Aq[4] = {1, 1, 1, 1};
        if (tid < kChunks) {
            float vb[4] = {predw, X.x, X.y, X.z};
            #pragma unroll
            for (int k = 0; k < 4; ++k) {
                float w   = __builtin_amdgcn_exp2f(
                                kPwm1 * __builtin_amdgcn_logf(vb[k]));
                float p3  = w * vb[k];
                float At  = fmaf(-c31, w, 1.0f);
                float Bt  = fmaf(c21, p3, Fc[k]);
                float Aqt = fmaf(-c1, w, 1.0f);       // 1 - c1*v^2.125 (free w)
                A[k] = At; B[k] = Bt; Aq[k] = Aqt;
                Qv = fmaf(At, Qv, Bt);     Pv = At * Pv;
                Qq = fmaf(Aqt, Qq, Bq[k]); Pq = Aqt * Pq;
            }
        }
        float xP = Pv, xQ = Qv, uP = Pq, uQ = Qq;
        wave_scan4(xP, xQ, uP, uQ);
        if (lane == 63) { SCv[wid] = make_float2(xP, xQ);
                          SCq[wid] = make_float2(uP, uQ); }
        __syncthreads();
        float eP = __shfl_up(xP, 1, 64), eQ = __shfl_up(xQ, 1, 64);
        float fP = __shfl_up(uP, 1, 64), fQ = __shfl_up(uQ, 1, 64);
        if (lane == 0) { eP = 1.f; eQ = 0.f; fP = 1.f; fQ = 0.f; }
        float2 a0 = SCv[0], a1 = SCv[1], a2 = SCv[2];
        float2 b0 = SCq[0], b1 = SCq[1], b2 = SCq[2];
        float wP = 1.f, wQ = 0.f, vP = 1.f, vQ = 0.f;
        if (wid >= 1) { wP = a0.x; wQ = a0.y; vP = b0.x; vQ = b0.y; }
        if (wid >= 2) { wQ = fmaf(a1.x, wQ, a1.y); wP *= a1.x;
                        vQ = fmaf(b1.x, vQ, b1.y); vP *= b1.x; }
        if (wid >= 3) { wQ = fmaf(a2.x, wQ, a2.y); wP *= a2.x;
                        vQ = fmaf(b2.x, vQ, b2.y); vP *= b2.x; }
        if (tid < kChunks) {
            float x = fmaf(eP, wQ, eQ) + eP * wP;     // v_{4tid}
            float q = fmaf(fP, vQ, fQ) + fP * vP;     // q_{4tid} (q_0 = 1)
            float yv[4];
            #pragma unroll
            for (int k = 0; k < 4; ++k) {
                x = fmaf(A[k],  x, B[k]);             // v_{t+1}
                q = fmaf(Aq[k], q, Bq[k]);            // q_{t+1}
                yv[k] = kV0 * (kK1 * (1.0f - q)
                             + kK2 * fmaf(-q, __builtin_amdgcn_rcpf(x), 1.0f)
                             + kK3 * (1.0f - x));
            }
            ((float4*)out)[tid] = make_float4(yv[0], yv[1], yv[2], yv[3]);
        }
    }
}

extern "C" void kernel_launch(void* const* d_in, const int* in_sizes, int n_in,
                              void* d_out, int out_size, void* d_ws, size_t ws_size,
                              hipStream_t stream) {
    bold_kernel<<<dim3(1), dim3(256), 0, stream>>>(d_in[0], (float*)d_out);
}